// Round 13
// baseline (822.612 us; speedup 1.0000x reference)
//
#include <hip/hip_runtime.h>
#include <hip/hip_cooperative_groups.h>

namespace cg = cooperative_groups;

#define NN 10000
#define NE 640000
#define DIM 128
#define CLS 40
#define MAXDEG 160
#define NSLICE 157   // ceil(10000/64) slices of 64 nodes
#define CAP 48       // staging capacity per (block,bin); mean occupancy 16
#define GRID 1024

typedef unsigned short u16;
typedef unsigned int u32;
typedef __attribute__((ext_vector_type(8))) short bf16x8;
typedef __attribute__((ext_vector_type(4))) float f32x4;
typedef __attribute__((ext_vector_type(4))) unsigned int u32x4;

// round-to-nearest-even fp32 -> bf16
__device__ __forceinline__ u16 f2bf(float f) {
    u32 u = __float_as_uint(f);
    u32 r = (u + 0x7fffu + ((u >> 16) & 1u)) >> 16;
    return (u16)r;
}

// ---------------- shared-memory union (max 20736 B) ----------------
union SMem {
    u32 lcnt[NSLICE];                              // bin phase
    struct { u16 slice[64 * MAXDEG]; u32 ldeg[64]; } build;
    u16 sidx[4][MAXDEG];                           // aggregate phase
    u16 Hs[4][16][136];                            // mm_cls phase
};

// ---------------- device phase functions ----------------

// bin 2500 edges into 157 dst-slices via LDS counters (unit = one of 256)
__device__ __forceinline__ void dev_bin(int unit, int t,
    const int* __restrict__ e_src, const int* __restrict__ e_dst,
    u32* __restrict__ staged, u16* __restrict__ cnt, u32* lcnt) {
    for (int i = t; i < NSLICE; i += 256) lcnt[i] = 0;
    __syncthreads();
    int base = unit * 2500;
    for (int j = t; j < 2500; j += 256) {
        int i = base + j;
        int d = __builtin_nontemporal_load(&e_dst[i]);
        int s = __builtin_nontemporal_load(&e_src[i]);
        int bin = d >> 6;
        int dl = d & 63;
        u32 r = atomicAdd(&lcnt[bin], 1u);
        if (r < CAP)
            staged[((u32)unit * NSLICE + bin) * CAP + r] = ((u32)dl << 14) | (u32)s;
    }
    __syncthreads();
    for (int i = t; i < NSLICE; i += 256)
        cnt[i * 256 + unit] = (u16)(lcnt[i] < CAP ? lcnt[i] : CAP);
}

// fp32 -> bf16 table, unit = 256 float4s
__device__ __forceinline__ void dev_cvt(int unit, int t,
    const float* __restrict__ features, u16* __restrict__ fb) {
    int i = unit * 256 + t;  // < 320000 = NN*DIM/4
    float4 v = ((const float4*)features)[i];
    ushort4 o;
    o.x = f2bf(v.x); o.y = f2bf(v.y); o.z = f2bf(v.z); o.w = f2bf(v.w);
    ((ushort4*)fb)[i] = o;
}

// pack one weight fragment unit (0..139), one wave per unit
__device__ __forceinline__ void dev_pack(int unit, int l,
    const float* __restrict__ Ws1, const float* __restrict__ Wn1,
    const float* __restrict__ Ws2, const float* __restrict__ Wn2,
    const float* __restrict__ Wc,
    u16* __restrict__ W1p, u16* __restrict__ W2p, u16* __restrict__ Wcp) {
    u16 v[8];
    if (unit < 128) {
        int which = unit >> 6;
        int idx = unit & 63;
        int ks = idx >> 3, n = idx & 7;
        const float* S = which ? Ws2 : Ws1;
        const float* Nw = which ? Wn2 : Wn1;
        u16* dst = which ? W2p : W1p;
        int col = n * 16 + (l & 15);
#pragma unroll
        for (int j = 0; j < 8; j++) {
            int k = ks * 32 + (l >> 4) * 8 + j;
            float f = (k < 128) ? S[k * 128 + col] : Nw[(k - 128) * 128 + col];
            v[j] = f2bf(f);
        }
        uint4 o;
        o.x = (u32)v[0] | ((u32)v[1] << 16);
        o.y = (u32)v[2] | ((u32)v[3] << 16);
        o.z = (u32)v[4] | ((u32)v[5] << 16);
        o.w = (u32)v[6] | ((u32)v[7] << 16);
        ((uint4*)dst)[idx * 64 + l] = o;
    } else if (unit < 140) {
        int idx = unit - 128;  // 0..11 = ks*3 + n
        int ks = idx / 3, n = idx - ks * 3;
        int col = n * 16 + (l & 15);
#pragma unroll
        for (int j = 0; j < 8; j++) {
            int k = ks * 32 + (l >> 4) * 8 + j;
            float f = (col < CLS) ? Wc[k * CLS + col] : 0.f;
            v[j] = f2bf(f);
        }
        uint4 o;
        o.x = (u32)v[0] | ((u32)v[1] << 16);
        o.y = (u32)v[2] | ((u32)v[3] << 16);
        o.z = (u32)v[4] | ((u32)v[5] << 16);
        o.w = (u32)v[6] | ((u32)v[7] << 16);
        ((uint4*)Wcp)[idx * 64 + l] = o;
    }
}

// build one 64-node padded-CSR slice in LDS (LDS atomics only)
__device__ __forceinline__ void dev_build(int b, int t,
    const u32* __restrict__ staged, const u16* __restrict__ cnt,
    int* __restrict__ deg, u16* __restrict__ edge_src,
    u16* slice, u32* ldeg) {
    int wv = t >> 6, lane = t & 63;
    for (int i = t; i < 64 * MAXDEG / 2; i += 256) ((u32*)slice)[i] = 0;
    for (int i = t; i < 64; i += 256) ldeg[i] = 0;
    __syncthreads();
    for (int blk = wv; blk < 256; blk += 4) {
        int c = (int)cnt[b * 256 + blk];
        if (lane < c) {
            u32 e = staged[((u32)blk * NSLICE + b) * CAP + lane];
            int dl = (int)(e >> 14);
            int src = (int)(e & 0x3fffu);
            u32 pos = atomicAdd(&ldeg[dl], 1u);
            if (pos < MAXDEG) slice[dl * MAXDEG + pos] = (u16)src;
        }
    }
    __syncthreads();
    int n0 = b * 64;
    for (int idx = t; idx < 64 * (MAXDEG / 8); idx += 256) {
        int row = idx / (MAXDEG / 8), col = idx % (MAXDEG / 8);
        if (n0 + row < NN)
            ((uint4*)(edge_src + (size_t)(n0 + row) * MAXDEG))[col] =
                *(uint4*)&slice[row * MAXDEG + col * 8];
    }
    __syncthreads();
    if (t < 64 && n0 + t < NN) deg[n0 + t] = (int)ldeg[t];
}

// mean-aggregate one node quad (unit u -> nodes 4u..4u+3, one wave each)
__device__ __forceinline__ void dev_agg(int u, int t,
    const u16* __restrict__ hb, const int* __restrict__ deg,
    const u16* __restrict__ edge_src, u16* __restrict__ hnb,
    u16 sidx[4][MAXDEG]) {
    int wv = t >> 6;
    int lane = t & 63;
    int node = u * 4 + wv;
    int q = lane >> 4;
    int l16 = lane & 15;
    int dg = deg[node];
    int dgc = dg < MAXDEG ? dg : MAXDEG;
    const u32* ep = (const u32*)(edge_src + (size_t)node * MAXDEG);  // 80 u32 words
    u32 e0 = __builtin_nontemporal_load(&ep[lane]);
    sidx[wv][2 * lane] = (u16)(e0 & 0xffffu);
    sidx[wv][2 * lane + 1] = (u16)(e0 >> 16);
    if (lane < 16) {
        u32 e1 = __builtin_nontemporal_load(&ep[64 + lane]);
        sidx[wv][128 + 2 * lane] = (u16)(e1 & 0xffffu);
        sidx[wv][128 + 2 * lane + 1] = (u16)(e1 >> 16);
    }
    const uint4* hp = (const uint4*)hb;
    float a0 = 0.f, a1 = 0.f, a2 = 0.f, a3 = 0.f, a4 = 0.f, a5 = 0.f, a6 = 0.f, a7 = 0.f;
#define BACC(v)                                     \
    do {                                            \
        a0 += __uint_as_float((v).x << 16);         \
        a1 += __uint_as_float((v).x & 0xffff0000u); \
        a2 += __uint_as_float((v).y << 16);         \
        a3 += __uint_as_float((v).y & 0xffff0000u); \
        a4 += __uint_as_float((v).z << 16);         \
        a5 += __uint_as_float((v).z & 0xffff0000u); \
        a6 += __uint_as_float((v).w << 16);         \
        a7 += __uint_as_float((v).w & 0xffff0000u); \
    } while (0)
    int e = 0;
    for (; e + 16 <= dgc; e += 16) {
        int i0 = (int)sidx[wv][e + q];
        int i1 = (int)sidx[wv][e + 4 + q];
        int i2 = (int)sidx[wv][e + 8 + q];
        int i3 = (int)sidx[wv][e + 12 + q];
        uint4 v0 = hp[i0 * 16 + l16];
        uint4 v1 = hp[i1 * 16 + l16];
        uint4 v2 = hp[i2 * 16 + l16];
        uint4 v3 = hp[i3 * 16 + l16];
        BACC(v0);
        BACC(v1);
        BACC(v2);
        BACC(v3);
    }
    for (; e + 4 <= dgc; e += 4) {
        int i0 = (int)sidx[wv][e + q];
        uint4 v = hp[i0 * 16 + l16];
        BACC(v);
    }
    if (e < dgc && e + q < dgc) {
        int i0 = (int)sidx[wv][e + q];
        uint4 v = hp[i0 * 16 + l16];
        BACC(v);
    }
#undef BACC
    a0 += __shfl_xor(a0, 16, 64); a1 += __shfl_xor(a1, 16, 64);
    a2 += __shfl_xor(a2, 16, 64); a3 += __shfl_xor(a3, 16, 64);
    a4 += __shfl_xor(a4, 16, 64); a5 += __shfl_xor(a5, 16, 64);
    a6 += __shfl_xor(a6, 16, 64); a7 += __shfl_xor(a7, 16, 64);
    a0 += __shfl_xor(a0, 32, 64); a1 += __shfl_xor(a1, 32, 64);
    a2 += __shfl_xor(a2, 32, 64); a3 += __shfl_xor(a3, 32, 64);
    a4 += __shfl_xor(a4, 32, 64); a5 += __shfl_xor(a5, 32, 64);
    a6 += __shfl_xor(a6, 32, 64); a7 += __shfl_xor(a7, 32, 64);
    if (q == 0) {
        float r = 1.0f / fmaxf((float)dg, 1.0f);
        u32x4 o;
        o.x = (u32)f2bf(a0 * r) | ((u32)f2bf(a1 * r) << 16);
        o.y = (u32)f2bf(a2 * r) | ((u32)f2bf(a3 * r) << 16);
        o.z = (u32)f2bf(a4 * r) | ((u32)f2bf(a5 * r) << 16);
        o.w = (u32)f2bf(a6 * r) | ((u32)f2bf(a7 * r) << 16);
        __builtin_nontemporal_store(o, (u32x4*)hnb + node * 16 + l16);
    }
}

// MFMA GEMM unit: 64 rows -> h1b = relu([hsb|hnb] @ W1p + b)
__device__ __forceinline__ void dev_mm(int u, int t,
    const u16* __restrict__ hsb, const u16* __restrict__ hnb,
    const u16* __restrict__ Bp, const float* __restrict__ bias,
    u16* __restrict__ outb) {
    int w = t >> 6, l = t & 63;
    int r16 = l & 15, kb = l >> 4;
    int row0 = u * 64 + w * 16;
    int arow = row0 + r16;
    if (arow > NN - 1) arow = NN - 1;
    const bf16x8* As = (const bf16x8*)hsb;
    const bf16x8* An = (const bf16x8*)hnb;
    const bf16x8* B = (const bf16x8*)Bp;
    f32x4 acc[8];
#pragma unroll
    for (int n = 0; n < 8; n++) { f32x4 z = {0.f, 0.f, 0.f, 0.f}; acc[n] = z; }
#pragma unroll
    for (int ks = 0; ks < 8; ks++) {
        bf16x8 a = (ks < 4) ? As[arow * 16 + ks * 4 + kb]
                            : An[arow * 16 + (ks - 4) * 4 + kb];
#pragma unroll
        for (int n = 0; n < 8; n++) {
            bf16x8 b = B[(ks * 8 + n) * 64 + l];
            acc[n] = __builtin_amdgcn_mfma_f32_16x16x32_bf16(a, b, acc[n], 0, 0, 0);
        }
    }
    int orow = row0 + kb * 4;
#pragma unroll
    for (int n = 0; n < 8; n++) {
        int col = n * 16 + r16;
        float bv = bias[col];
#pragma unroll
        for (int r = 0; r < 4; r++) {
            int rr = orow + r;
            if (rr < NN) outb[rr * 128 + col] = f2bf(fmaxf(acc[n][r] + bv, 0.f));
        }
    }
}

// MFMA GEMM + classifier unit: 64 rows
__device__ __forceinline__ void dev_mm_cls(int u, int t,
    const u16* __restrict__ hsb, const u16* __restrict__ hnb,
    const u16* __restrict__ Bp, const float* __restrict__ bias,
    const u16* __restrict__ Bc, const float* __restrict__ bc,
    float* __restrict__ out, u16 Hs[4][16][136]) {
    int w = t >> 6, l = t & 63;
    int r16 = l & 15, kb = l >> 4;
    int row0 = u * 64 + w * 16;
    int arow = row0 + r16;
    if (arow > NN - 1) arow = NN - 1;
    const bf16x8* As = (const bf16x8*)hsb;
    const bf16x8* An = (const bf16x8*)hnb;
    const bf16x8* B = (const bf16x8*)Bp;
    f32x4 acc[8];
#pragma unroll
    for (int n = 0; n < 8; n++) { f32x4 z = {0.f, 0.f, 0.f, 0.f}; acc[n] = z; }
#pragma unroll
    for (int ks = 0; ks < 8; ks++) {
        bf16x8 a = (ks < 4) ? As[arow * 16 + ks * 4 + kb]
                            : An[arow * 16 + (ks - 4) * 4 + kb];
#pragma unroll
        for (int n = 0; n < 8; n++) {
            bf16x8 b = B[(ks * 8 + n) * 64 + l];
            acc[n] = __builtin_amdgcn_mfma_f32_16x16x32_bf16(a, b, acc[n], 0, 0, 0);
        }
    }
#pragma unroll
    for (int n = 0; n < 8; n++) {
        int col = n * 16 + r16;
        float bv = bias[col];
#pragma unroll
        for (int r = 0; r < 4; r++) {
            Hs[w][kb * 4 + r][col] = f2bf(fmaxf(acc[n][r] + bv, 0.f));
        }
    }
    __syncthreads();
    f32x4 cacc[3];
#pragma unroll
    for (int n = 0; n < 3; n++) { f32x4 z = {0.f, 0.f, 0.f, 0.f}; cacc[n] = z; }
#pragma unroll
    for (int ks = 0; ks < 4; ks++) {
        bf16x8 a = *(const bf16x8*)&Hs[w][r16][ks * 32 + kb * 8];
#pragma unroll
        for (int n = 0; n < 3; n++) {
            bf16x8 b = ((const bf16x8*)Bc)[(ks * 3 + n) * 64 + l];
            cacc[n] = __builtin_amdgcn_mfma_f32_16x16x32_bf16(a, b, cacc[n], 0, 0, 0);
        }
    }
    __syncthreads();
    int orow = row0 + kb * 4;
#pragma unroll
    for (int n = 0; n < 3; n++) {
        int col = n * 16 + r16;
        if (col < CLS) {
            float bcv = bc[col];
#pragma unroll
            for (int r = 0; r < 4; r++) {
                int rr = orow + r;
                if (rr < NN) out[rr * CLS + col] = cacc[n][r] + bcv;
            }
        }
    }
}

// ---------------- cooperative mega-kernel ----------------

__global__ __launch_bounds__(256, 4) void k_mega(
    const int* e_src, const int* e_dst, const float* features,
    const float* Ws1, const float* Wn1, const float* b1,
    const float* Ws2, const float* Wn2, const float* b2,
    const float* Wc, const float* bc,
    u32* staged, u16* cnt, int* deg, u16* edge_srcb,
    u16* fb, u16* hnb, u16* h1b,
    u16* W1p, u16* W2p, u16* Wcp, float* out) {
    __shared__ SMem sm;
    cg::grid_group grid = cg::this_grid();
    int bid = blockIdx.x;
    int t = threadIdx.x;
    // P0: bin | cvt | pack
    if (bid < 256) {
        dev_bin(bid, t, e_src, e_dst, staged, cnt, sm.lcnt);
    } else {
        for (int u = bid - 256; u < 1250; u += 768) dev_cvt(u, t, features, fb);
        if (bid >= 989)
            dev_pack((bid - 989) * 4 + (t >> 6), t & 63,
                     Ws1, Wn1, Ws2, Wn2, Wc, W1p, W2p, Wcp);
    }
    grid.sync();
    // P1: build CSR slices
    for (int u = bid; u < NSLICE; u += GRID)
        dev_build(u, t, staged, cnt, deg, edge_srcb, sm.build.slice, sm.build.ldeg);
    grid.sync();
    // P2: aggregate layer 1
    for (int u = bid; u < NN / 4; u += GRID)
        dev_agg(u, t, fb, deg, edge_srcb, hnb, sm.sidx);
    grid.sync();
    // P3: mm layer 1
    for (int u = bid; u < (NN + 63) / 64; u += GRID)
        dev_mm(u, t, fb, hnb, W1p, b1, h1b);
    grid.sync();
    // P4: aggregate layer 2
    for (int u = bid; u < NN / 4; u += GRID)
        dev_agg(u, t, h1b, deg, edge_srcb, hnb, sm.sidx);
    grid.sync();
    // P5: mm layer 2 + classifier
    for (int u = bid; u < (NN + 63) / 64; u += GRID)
        dev_mm_cls(u, t, h1b, hnb, W2p, b2, Wcp, bc, out, sm.Hs);
}

// ---------------- fallback separate kernels (round-11 structure) ----------------

__global__ __launch_bounds__(256) void k_prep(
    const int* __restrict__ e_src, const int* __restrict__ e_dst,
    u32* __restrict__ staged, u16* __restrict__ cnt,
    const float* __restrict__ features, u16* __restrict__ fb,
    const float* __restrict__ Ws1, const float* __restrict__ Wn1,
    const float* __restrict__ Ws2, const float* __restrict__ Wn2,
    const float* __restrict__ Wc,
    u16* __restrict__ W1p, u16* __restrict__ W2p, u16* __restrict__ Wcp) {
    __shared__ u32 lcnt[NSLICE];
    int bid = blockIdx.x, t = threadIdx.x;
    if (bid < 256) dev_bin(bid, t, e_src, e_dst, staged, cnt, lcnt);
    else if (bid < 1506) dev_cvt(bid - 256, t, features, fb);
    else dev_pack((bid - 1506) * 4 + (t >> 6), t & 63, Ws1, Wn1, Ws2, Wn2, Wc, W1p, W2p, Wcp);
}

__global__ __launch_bounds__(256) void k_build(
    const u32* __restrict__ staged, const u16* __restrict__ cnt,
    int* __restrict__ deg, u16* __restrict__ edge_src) {
    __shared__ u16 slice[64 * MAXDEG];
    __shared__ u32 ldeg[64];
    dev_build(blockIdx.x, threadIdx.x, staged, cnt, deg, edge_src, slice, ldeg);
}

__global__ __launch_bounds__(256) void k_aggregate(
    const u16* __restrict__ hb, const int* __restrict__ deg,
    const u16* __restrict__ edge_src, u16* __restrict__ hnb) {
    __shared__ u16 sidx[4][MAXDEG];
    dev_agg(blockIdx.x, threadIdx.x, hb, deg, edge_src, hnb, sidx);
}

__global__ __launch_bounds__(256) void k_mm(
    const u16* __restrict__ hsb, const u16* __restrict__ hnb,
    const u16* __restrict__ Bp, const float* __restrict__ bias,
    u16* __restrict__ outb) {
    dev_mm(blockIdx.x, threadIdx.x, hsb, hnb, Bp, bias, outb);
}

__global__ __launch_bounds__(256) void k_mm_cls(
    const u16* __restrict__ hsb, const u16* __restrict__ hnb,
    const u16* __restrict__ Bp, const float* __restrict__ bias,
    const u16* __restrict__ Bc, const float* __restrict__ bc,
    float* __restrict__ out) {
    __shared__ u16 Hs[4][16][136];
    dev_mm_cls(blockIdx.x, threadIdx.x, hsb, hnb, Bp, bias, Bc, bc, out, Hs);
}

// ---------------- launch ----------------

static inline size_t align_up(size_t x, size_t a) { return (x + a - 1) & ~(a - 1); }

extern "C" void kernel_launch(void* const* d_in, const int* in_sizes, int n_in,
                              void* d_out, int out_size, void* d_ws, size_t ws_size,
                              hipStream_t stream) {
    const float* features = (const float*)d_in[0];
    const int* edge_index = (const int*)d_in[1];
    const float* Ws1 = (const float*)d_in[2];
    const float* Wn1 = (const float*)d_in[3];
    const float* b1 = (const float*)d_in[4];
    const float* Ws2 = (const float*)d_in[5];
    const float* Wn2 = (const float*)d_in[6];
    const float* b2 = (const float*)d_in[7];
    const float* Wc = (const float*)d_in[8];
    const float* bc = (const float*)d_in[9];
    float* out = (float*)d_out;

    const int* e_src = edge_index;
    const int* e_dst = edge_index + NE;

    char* ws = (char*)d_ws;
    size_t off = 0;
    int* deg = (int*)(ws + off);       off = align_up(off + NN * 4, 512);
    u32* staged = (u32*)(ws + off);    off = align_up(off + (size_t)256 * NSLICE * CAP * 4, 512);
    u16* cnt = (u16*)(ws + off);       off = align_up(off + (size_t)NSLICE * 256 * 2, 512);
    u16* edge_srcb = (u16*)(ws + off); off = align_up(off + (size_t)NN * MAXDEG * 2, 512);
    u16* fb = (u16*)(ws + off);        off = align_up(off + (size_t)NN * DIM * 2, 512);
    u16* hnb = (u16*)(ws + off);       off = align_up(off + (size_t)NN * DIM * 2, 512);
    u16* h1b = (u16*)(ws + off);       off = align_up(off + (size_t)NN * DIM * 2, 512);
    u16* W1p = (u16*)(ws + off);       off = align_up(off + 8 * 8 * 64 * 8 * 2, 512);
    u16* W2p = (u16*)(ws + off);       off = align_up(off + 8 * 8 * 64 * 8 * 2, 512);
    u16* Wcp = (u16*)(ws + off);       off = align_up(off + 4 * 3 * 64 * 8 * 2, 512);

    void* args[] = {
        (void*)&e_src, (void*)&e_dst, (void*)&features,
        (void*)&Ws1, (void*)&Wn1, (void*)&b1,
        (void*)&Ws2, (void*)&Wn2, (void*)&b2,
        (void*)&Wc, (void*)&bc,
        (void*)&staged, (void*)&cnt, (void*)&deg, (void*)&edge_srcb,
        (void*)&fb, (void*)&hnb, (void*)&h1b,
        (void*)&W1p, (void*)&W2p, (void*)&Wcp, (void*)&out};
    hipError_t err = hipLaunchCooperativeKernel(
        (const void*)k_mega, dim3(GRID), dim3(256), args, 0, stream);

    if (err != hipSuccess) {
        // fallback: proven separate-kernel pipeline (round-11 structure)
        k_prep<<<1541, 256, 0, stream>>>(e_src, e_dst, staged, cnt, features, fb,
                                         Ws1, Wn1, Ws2, Wn2, Wc, W1p, W2p, Wcp);
        k_build<<<NSLICE, 256, 0, stream>>>(staged, cnt, deg, edge_srcb);
        k_aggregate<<<NN / 4, 256, 0, stream>>>(fb, deg, edge_srcb, hnb);
        k_mm<<<(NN + 63) / 64, 256, 0, stream>>>(fb, hnb, W1p, b1, h1b);
        k_aggregate<<<NN / 4, 256, 0, stream>>>(h1b, deg, edge_srcb, hnb);
        k_mm_cls<<<(NN + 63) / 64, 256, 0, stream>>>(h1b, hnb, W2p, b2, Wcp, bc, out);
    }
}

// Round 14
// 144.512 us; speedup vs baseline: 5.6923x; 5.6923x over previous
//
#include <hip/hip_runtime.h>

#define NN 10000
#define NE 640000
#define DIM 128
#define CLS 40
#define MAXDEG 160
#define NBIN 625     // 16-node bins
#define CAPB 24      // staging capacity per (block,bin); Poisson mean 4, P(>24)~1e-11
#define TPB_F 1024

typedef unsigned short u16;
typedef unsigned int u32;
typedef __attribute__((ext_vector_type(8))) short bf16x8;
typedef __attribute__((ext_vector_type(4))) float f32x4;

// round-to-nearest-even fp32 -> bf16
__device__ __forceinline__ u16 f2bf(float f) {
    u32 u = __float_as_uint(f);
    u32 r = (u + 0x7fffu + ((u >> 16) & 1u)) >> 16;
    return (u16)r;
}

// ---------------- prep: bin edges | cvt features | pack weights ----------------
// blocks [0,256): bin 2500 edges into 625 16-node bins via LDS counters
// blocks [256,1506): fp32->bf16 cvt | [1506,1541): weight pack

__global__ __launch_bounds__(256) void k_prep(
    const int* __restrict__ e_src, const int* __restrict__ e_dst,
    u32* __restrict__ staged, u16* __restrict__ cnt,
    const float* __restrict__ features, u16* __restrict__ fb,
    const float* __restrict__ Ws1, const float* __restrict__ Wn1,
    const float* __restrict__ Ws2, const float* __restrict__ Wn2,
    const float* __restrict__ Wc,
    u16* __restrict__ W1p, u16* __restrict__ W2p, u16* __restrict__ Wcp) {
    int bid = blockIdx.x;
    int t = threadIdx.x;
    if (bid < 256) {
        __shared__ u32 lcnt[NBIN];
        for (int i = t; i < NBIN; i += 256) lcnt[i] = 0;
        __syncthreads();
        int base = bid * 2500;
        for (int j = t; j < 2500; j += 256) {
            int i = base + j;
            int d = __builtin_nontemporal_load(&e_dst[i]);
            int s = __builtin_nontemporal_load(&e_src[i]);
            int bin = d >> 4;
            int dl = d & 15;
            u32 r = atomicAdd(&lcnt[bin], 1u);
            if (r < CAPB)
                staged[((u32)bid * NBIN + bin) * CAPB + r] = ((u32)dl << 14) | (u32)s;
        }
        __syncthreads();
        for (int i = t; i < NBIN; i += 256)
            cnt[i * 256 + bid] = (u16)(lcnt[i] < CAPB ? lcnt[i] : CAPB);
    } else if (bid < 1506) {
        int i = (bid - 256) * 256 + t;  // < 320000 = NN*DIM/4
        float4 v = ((const float4*)features)[i];
        ushort4 o;
        o.x = f2bf(v.x); o.y = f2bf(v.y); o.z = f2bf(v.z); o.w = f2bf(v.w);
        ((ushort4*)fb)[i] = o;
    } else {
        int unit = (bid - 1506) * 4 + (t >> 6);  // 0..139
        int l = t & 63;
        u16 v[8];
        if (unit < 128) {
            int which = unit >> 6;
            int idx = unit & 63;
            int ks = idx >> 3, n = idx & 7;
            const float* S = which ? Ws2 : Ws1;
            const float* Nw = which ? Wn2 : Wn1;
            u16* dst = which ? W2p : W1p;
            int col = n * 16 + (l & 15);
#pragma unroll
            for (int j = 0; j < 8; j++) {
                int k = ks * 32 + (l >> 4) * 8 + j;
                float f = (k < 128) ? S[k * 128 + col] : Nw[(k - 128) * 128 + col];
                v[j] = f2bf(f);
            }
            uint4 o;
            o.x = (u32)v[0] | ((u32)v[1] << 16);
            o.y = (u32)v[2] | ((u32)v[3] << 16);
            o.z = (u32)v[4] | ((u32)v[5] << 16);
            o.w = (u32)v[6] | ((u32)v[7] << 16);
            ((uint4*)dst)[idx * 64 + l] = o;
        } else if (unit < 140) {
            int idx = unit - 128;  // 0..11 = ks*3 + n
            int ks = idx / 3, n = idx - ks * 3;
            int col = n * 16 + (l & 15);
#pragma unroll
            for (int j = 0; j < 8; j++) {
                int k = ks * 32 + (l >> 4) * 8 + j;
                float f = (col < CLS) ? Wc[k * CLS + col] : 0.f;
                v[j] = f2bf(f);
            }
            uint4 o;
            o.x = (u32)v[0] | ((u32)v[1] << 16);
            o.y = (u32)v[2] | ((u32)v[3] << 16);
            o.z = (u32)v[4] | ((u32)v[5] << 16);
            o.w = (u32)v[6] | ((u32)v[7] << 16);
            ((uint4*)Wcp)[idx * 64 + l] = o;
        }
    }
}

// ---------------- device helpers ----------------

// aggregate one node (one wave), edges from LDS slice row, write A-fragment to LDS
__device__ __forceinline__ void agg_node(
    int w, int lane, const u16* srow, int dg, const u16* __restrict__ hb,
    u16 aFrag[16][16][8]) {
    int q = lane >> 4;
    int l16 = lane & 15;
    int dgc = dg < MAXDEG ? dg : MAXDEG;
    const uint4* hp = (const uint4*)hb;
    float a0 = 0.f, a1 = 0.f, a2 = 0.f, a3 = 0.f, a4 = 0.f, a5 = 0.f, a6 = 0.f, a7 = 0.f;
#define BACC(v)                                     \
    do {                                            \
        a0 += __uint_as_float((v).x << 16);         \
        a1 += __uint_as_float((v).x & 0xffff0000u); \
        a2 += __uint_as_float((v).y << 16);         \
        a3 += __uint_as_float((v).y & 0xffff0000u); \
        a4 += __uint_as_float((v).z << 16);         \
        a5 += __uint_as_float((v).z & 0xffff0000u); \
        a6 += __uint_as_float((v).w << 16);         \
        a7 += __uint_as_float((v).w & 0xffff0000u); \
    } while (0)
    int e = 0;
    for (; e + 16 <= dgc; e += 16) {
        int i0 = (int)srow[e + q];
        int i1 = (int)srow[e + 4 + q];
        int i2 = (int)srow[e + 8 + q];
        int i3 = (int)srow[e + 12 + q];
        uint4 v0 = hp[i0 * 16 + l16];
        uint4 v1 = hp[i1 * 16 + l16];
        uint4 v2 = hp[i2 * 16 + l16];
        uint4 v3 = hp[i3 * 16 + l16];
        BACC(v0);
        BACC(v1);
        BACC(v2);
        BACC(v3);
    }
    for (; e + 4 <= dgc; e += 4) {
        int i0 = (int)srow[e + q];
        uint4 v = hp[i0 * 16 + l16];
        BACC(v);
    }
    if (e < dgc && e + q < dgc) {
        int i0 = (int)srow[e + q];
        uint4 v = hp[i0 * 16 + l16];
        BACC(v);
    }
#undef BACC
    a0 += __shfl_xor(a0, 16, 64); a1 += __shfl_xor(a1, 16, 64);
    a2 += __shfl_xor(a2, 16, 64); a3 += __shfl_xor(a3, 16, 64);
    a4 += __shfl_xor(a4, 16, 64); a5 += __shfl_xor(a5, 16, 64);
    a6 += __shfl_xor(a6, 16, 64); a7 += __shfl_xor(a7, 16, 64);
    a0 += __shfl_xor(a0, 32, 64); a1 += __shfl_xor(a1, 32, 64);
    a2 += __shfl_xor(a2, 32, 64); a3 += __shfl_xor(a3, 32, 64);
    a4 += __shfl_xor(a4, 32, 64); a5 += __shfl_xor(a5, 32, 64);
    a6 += __shfl_xor(a6, 32, 64); a7 += __shfl_xor(a7, 32, 64);
    if (q == 0) {
        float r = 1.0f / fmaxf((float)dg, 1.0f);
        uint4 o;
        o.x = (u32)f2bf(a0 * r) | ((u32)f2bf(a1 * r) << 16);
        o.y = (u32)f2bf(a2 * r) | ((u32)f2bf(a3 * r) << 16);
        o.z = (u32)f2bf(a4 * r) | ((u32)f2bf(a5 * r) << 16);
        o.w = (u32)f2bf(a6 * r) | ((u32)f2bf(a7 * r) << 16);
        *(uint4*)&aFrag[l16][w][0] = o;  // chunk=l16 (cols l16*8..+7), row=w
    }
}

// one wave computes one 16-col fragment of relu([hs|hn]@W + b), writing global bf16
__device__ __forceinline__ void mm_frag(
    int n, int lane, int nb, const u16* __restrict__ hsb,
    const u16 aFrag[16][16][8], const u16* __restrict__ Bp,
    const float* __restrict__ bias, u16* __restrict__ outb) {
    int r16 = lane & 15, kb = lane >> 4;
    int arow = nb * 16 + r16;
    const bf16x8* As = (const bf16x8*)hsb;
    const bf16x8* B = (const bf16x8*)Bp;
    f32x4 acc = {0.f, 0.f, 0.f, 0.f};
#pragma unroll
    for (int ks = 0; ks < 8; ks++) {
        bf16x8 a = (ks < 4) ? As[arow * 16 + ks * 4 + kb]
                            : *(const bf16x8*)&aFrag[(ks - 4) * 4 + kb][r16][0];
        bf16x8 b = B[(ks * 8 + n) * 64 + lane];
        acc = __builtin_amdgcn_mfma_f32_16x16x32_bf16(a, b, acc, 0, 0, 0);
    }
    int col = n * 16 + r16;
    float bv = bias[col];
    int orow = nb * 16 + kb * 4;
#pragma unroll
    for (int r = 0; r < 4; r++)
        outb[(orow + r) * 128 + col] = f2bf(fmaxf(acc[r] + bv, 0.f));
}

// same but write relu result into the LDS h2 fragment tile (for classifier)
__device__ __forceinline__ void mm_frag_lds(
    int n, int lane, int nb, const u16* __restrict__ hsb,
    const u16 aFrag[16][16][8], const u16* __restrict__ Bp,
    const float* __restrict__ bias, u16 h2Frag[16][16][8]) {
    int r16 = lane & 15, kb = lane >> 4;
    int arow = nb * 16 + r16;
    const bf16x8* As = (const bf16x8*)hsb;
    const bf16x8* B = (const bf16x8*)Bp;
    f32x4 acc = {0.f, 0.f, 0.f, 0.f};
#pragma unroll
    for (int ks = 0; ks < 8; ks++) {
        bf16x8 a = (ks < 4) ? As[arow * 16 + ks * 4 + kb]
                            : *(const bf16x8*)&aFrag[(ks - 4) * 4 + kb][r16][0];
        bf16x8 b = B[(ks * 8 + n) * 64 + lane];
        acc = __builtin_amdgcn_mfma_f32_16x16x32_bf16(a, b, acc, 0, 0, 0);
    }
    int col = n * 16 + r16;
    float bv = bias[col];
    int ch = col >> 3, el = col & 7;
#pragma unroll
    for (int r = 0; r < 4; r++)
        h2Frag[ch][kb * 4 + r][el] = f2bf(fmaxf(acc[r] + bv, 0.f));
}

// classifier fragment: one wave, 16 cols of out = h2 @ Wc + bc
__device__ __forceinline__ void cls_frag(
    int n, int lane, int nb, const u16 h2Frag[16][16][8],
    const u16* __restrict__ Bc, const float* __restrict__ bc,
    float* __restrict__ out) {
    int r16 = lane & 15, kb = lane >> 4;
    const bf16x8* B = (const bf16x8*)Bc;
    f32x4 acc = {0.f, 0.f, 0.f, 0.f};
#pragma unroll
    for (int ks = 0; ks < 4; ks++) {
        bf16x8 a = *(const bf16x8*)&h2Frag[ks * 4 + kb][r16][0];
        bf16x8 b = B[(ks * 3 + n) * 64 + lane];
        acc = __builtin_amdgcn_mfma_f32_16x16x32_bf16(a, b, acc, 0, 0, 0);
    }
    int col = n * 16 + r16;
    if (col < CLS) {
        float bcv = bc[col];
        int orow = nb * 16 + kb * 4;
#pragma unroll
        for (int r = 0; r < 4; r++)
            out[(orow + r) * CLS + col] = acc[r] + bcv;
    }
}

// ---------------- fuse1: build CSR tile + aggregate L1 + GEMM L1 ----------------
// block = 16 nodes, 16 waves (1 node/wave for aggregation)

__global__ __launch_bounds__(TPB_F, 8) void k_fuse1(
    const u32* __restrict__ staged, const u16* __restrict__ cnt,
    const u16* __restrict__ fb, const u16* __restrict__ W1p,
    const float* __restrict__ b1,
    int* __restrict__ deg, u16* __restrict__ edge_srcb, u16* __restrict__ h1b) {
    __shared__ u16 slice[16 * MAXDEG];
    __shared__ u32 ldeg[16];
    __shared__ u16 aFrag[16][16][8];
    int t = threadIdx.x, w = t >> 6, lane = t & 63, nb = blockIdx.x;
    for (int i = t; i < 16 * MAXDEG / 2; i += TPB_F) ((u32*)slice)[i] = 0;
    if (t < 16) ldeg[t] = 0;
    __syncthreads();
    // drain staged cells (LDS atomics only)
    for (int blk = w; blk < 256; blk += 16) {
        int c = (int)cnt[nb * 256 + blk];
        if (lane < c) {
            u32 e = staged[((u32)blk * NBIN + nb) * CAPB + lane];
            int dl = (int)(e >> 14);
            u32 pos = atomicAdd(&ldeg[dl], 1u);
            if (pos < MAXDEG) slice[dl * MAXDEG + pos] = (u16)(e & 0x3fffu);
        }
    }
    __syncthreads();
    // persist CSR tile for fuse2 (coalesced)
    for (int idx = t; idx < 16 * (MAXDEG / 8); idx += TPB_F) {
        int row = idx / (MAXDEG / 8), col = idx % (MAXDEG / 8);
        ((uint4*)(edge_srcb + (size_t)(nb * 16 + row) * MAXDEG))[col] =
            *(const uint4*)&slice[row * MAXDEG + col * 8];
    }
    if (t < 16) deg[nb * 16 + t] = (int)ldeg[t];
    // aggregate: one node per wave, from LDS edge list
    agg_node(w, lane, &slice[w * MAXDEG], (int)ldeg[w], fb, aFrag);
    __syncthreads();
    // GEMM: waves 0-7 each compute one 16-col fragment
    if (w < 8) mm_frag(w, lane, nb, fb, aFrag, W1p, b1, h1b);
}

// ---------------- fuse2: load CSR tile + aggregate L2 + GEMM L2 + classifier ----------------

__global__ __launch_bounds__(TPB_F, 8) void k_fuse2(
    const int* __restrict__ deg, const u16* __restrict__ edge_srcb,
    const u16* __restrict__ h1b, const u16* __restrict__ W2p,
    const float* __restrict__ b2, const u16* __restrict__ Wcp,
    const float* __restrict__ bc, float* __restrict__ out) {
    __shared__ u16 slice[16 * MAXDEG];
    __shared__ u32 ldeg[16];
    __shared__ u16 aFrag[16][16][8];
    __shared__ u16 h2Frag[16][16][8];
    int t = threadIdx.x, w = t >> 6, lane = t & 63, nb = blockIdx.x;
    for (int idx = t; idx < 16 * (MAXDEG / 8); idx += TPB_F) {
        int row = idx / (MAXDEG / 8), col = idx % (MAXDEG / 8);
        *(uint4*)&slice[row * MAXDEG + col * 8] =
            ((const uint4*)(edge_srcb + (size_t)(nb * 16 + row) * MAXDEG))[col];
    }
    if (t < 16) ldeg[t] = (u32)deg[nb * 16 + t];
    __syncthreads();
    agg_node(w, lane, &slice[w * MAXDEG], (int)ldeg[w], h1b, aFrag);
    __syncthreads();
    if (w < 8) mm_frag_lds(w, lane, nb, h1b, aFrag, W2p, b2, h2Frag);
    __syncthreads();
    if (w < 3) cls_frag(w, lane, nb, h2Frag, Wcp, bc, out);
}

// ---------------- launch ----------------

static inline size_t align_up(size_t x, size_t a) { return (x + a - 1) & ~(a - 1); }

extern "C" void kernel_launch(void* const* d_in, const int* in_sizes, int n_in,
                              void* d_out, int out_size, void* d_ws, size_t ws_size,
                              hipStream_t stream) {
    const float* features = (const float*)d_in[0];
    const int* edge_index = (const int*)d_in[1];
    const float* Ws1 = (const float*)d_in[2];
    const float* Wn1 = (const float*)d_in[3];
    const float* b1 = (const float*)d_in[4];
    const float* Ws2 = (const float*)d_in[5];
    const float* Wn2 = (const float*)d_in[6];
    const float* b2 = (const float*)d_in[7];
    const float* Wc = (const float*)d_in[8];
    const float* bc = (const float*)d_in[9];
    float* out = (float*)d_out;

    const int* e_src = edge_index;
    const int* e_dst = edge_index + NE;

    char* ws = (char*)d_ws;
    size_t off = 0;
    int* deg = (int*)(ws + off);       off = align_up(off + NN * 4, 512);
    u32* staged = (u32*)(ws + off);    off = align_up(off + (size_t)256 * NBIN * CAPB * 4, 512);
    u16* cnt = (u16*)(ws + off);       off = align_up(off + (size_t)NBIN * 256 * 2, 512);
    u16* edge_srcb = (u16*)(ws + off); off = align_up(off + (size_t)NN * MAXDEG * 2, 512);
    u16* fb = (u16*)(ws + off);        off = align_up(off + (size_t)NN * DIM * 2, 512);
    u16* h1b = (u16*)(ws + off);       off = align_up(off + (size_t)NN * DIM * 2, 512);
    u16* W1p = (u16*)(ws + off);       off = align_up(off + 8 * 8 * 64 * 8 * 2, 512);
    u16* W2p = (u16*)(ws + off);       off = align_up(off + 8 * 8 * 64 * 8 * 2, 512);
    u16* Wcp = (u16*)(ws + off);       off = align_up(off + 4 * 3 * 64 * 8 * 2, 512);

    // P0: bin edges + cvt features + pack weights
    k_prep<<<1541, 256, 0, stream>>>(e_src, e_dst, staged, cnt, features, fb,
                                     Ws1, Wn1, Ws2, Wn2, Wc, W1p, W2p, Wcp);
    // P1: build+agg+mm layer 1 (writes CSR + h1b)
    k_fuse1<<<NN / 16, TPB_F, 0, stream>>>(staged, cnt, fb, W1p, b1,
                                           deg, edge_srcb, h1b);
    // P2: load CSR + agg + mm layer 2 + classifier
    k_fuse2<<<NN / 16, TPB_F, 0, stream>>>(deg, edge_srcb, h1b, W2p, b2,
                                           Wcp, bc, out);
}

// Round 15
// 142.737 us; speedup vs baseline: 5.7631x; 1.0124x over previous
//
#include <hip/hip_runtime.h>

#define NN 10000
#define NE 640000
#define DIM 128
#define CLS 40
#define MAXDEG 160
#define NBIN 625     // 16-node bins
#define CAPB 24      // staging capacity per (block,bin); Poisson mean 4, P(>24)~1e-11
#define TPB_F 512

typedef unsigned short u16;
typedef unsigned int u32;
typedef __attribute__((ext_vector_type(8))) short bf16x8;
typedef __attribute__((ext_vector_type(4))) float f32x4;

// round-to-nearest-even fp32 -> bf16
__device__ __forceinline__ u16 f2bf(float f) {
    u32 u = __float_as_uint(f);
    u32 r = (u + 0x7fffu + ((u >> 16) & 1u)) >> 16;
    return (u16)r;
}

// ---------------- prep: bin edges | cvt features | pack weights ----------------
// blocks [0,256): bin 2500 edges into 625 16-node bins via LDS counters
// blocks [256,1506): fp32->bf16 cvt | [1506,1541): weight pack

__global__ __launch_bounds__(256) void k_prep(
    const int* __restrict__ e_src, const int* __restrict__ e_dst,
    u32* __restrict__ staged, u16* __restrict__ cnt,
    const float* __restrict__ features, u16* __restrict__ fb,
    const float* __restrict__ Ws1, const float* __restrict__ Wn1,
    const float* __restrict__ Ws2, const float* __restrict__ Wn2,
    const float* __restrict__ Wc,
    u16* __restrict__ W1p, u16* __restrict__ W2p, u16* __restrict__ Wcp) {
    int bid = blockIdx.x;
    int t = threadIdx.x;
    if (bid < 256) {
        __shared__ u32 lcnt[NBIN];
        for (int i = t; i < NBIN; i += 256) lcnt[i] = 0;
        __syncthreads();
        int base = bid * 2500;
        for (int j = t; j < 2500; j += 256) {
            int i = base + j;
            int d = __builtin_nontemporal_load(&e_dst[i]);
            int s = __builtin_nontemporal_load(&e_src[i]);
            int bin = d >> 4;
            int dl = d & 15;
            u32 r = atomicAdd(&lcnt[bin], 1u);
            if (r < CAPB)
                staged[((u32)bid * NBIN + bin) * CAPB + r] = ((u32)dl << 14) | (u32)s;
        }
        __syncthreads();
        for (int i = t; i < NBIN; i += 256)
            cnt[i * 256 + bid] = (u16)(lcnt[i] < CAPB ? lcnt[i] : CAPB);
    } else if (bid < 1506) {
        int i = (bid - 256) * 256 + t;  // < 320000 = NN*DIM/4
        float4 v = ((const float4*)features)[i];
        ushort4 o;
        o.x = f2bf(v.x); o.y = f2bf(v.y); o.z = f2bf(v.z); o.w = f2bf(v.w);
        ((ushort4*)fb)[i] = o;
    } else {
        int unit = (bid - 1506) * 4 + (t >> 6);  // 0..139
        int l = t & 63;
        u16 v[8];
        if (unit < 128) {
            int which = unit >> 6;
            int idx = unit & 63;
            int ks = idx >> 3, n = idx & 7;
            const float* S = which ? Ws2 : Ws1;
            const float* Nw = which ? Wn2 : Wn1;
            u16* dst = which ? W2p : W1p;
            int col = n * 16 + (l & 15);
#pragma unroll
            for (int j = 0; j < 8; j++) {
                int k = ks * 32 + (l >> 4) * 8 + j;
                float f = (k < 128) ? S[k * 128 + col] : Nw[(k - 128) * 128 + col];
                v[j] = f2bf(f);
            }
            uint4 o;
            o.x = (u32)v[0] | ((u32)v[1] << 16);
            o.y = (u32)v[2] | ((u32)v[3] << 16);
            o.z = (u32)v[4] | ((u32)v[5] << 16);
            o.w = (u32)v[6] | ((u32)v[7] << 16);
            ((uint4*)dst)[idx * 64 + l] = o;
        } else if (unit < 140) {
            int idx = unit - 128;  // 0..11 = ks*3 + n
            int ks = idx / 3, n = idx - ks * 3;
            int col = n * 16 + (l & 15);
#pragma unroll
            for (int j = 0; j < 8; j++) {
                int k = ks * 32 + (l >> 4) * 8 + j;
                float f = (col < CLS) ? Wc[k * CLS + col] : 0.f;
                v[j] = f2bf(f);
            }
            uint4 o;
            o.x = (u32)v[0] | ((u32)v[1] << 16);
            o.y = (u32)v[2] | ((u32)v[3] << 16);
            o.z = (u32)v[4] | ((u32)v[5] << 16);
            o.w = (u32)v[6] | ((u32)v[7] << 16);
            ((uint4*)Wcp)[idx * 64 + l] = o;
        }
    }
}

// ---------------- device helpers ----------------

// aggregate one node (one wave), edges from LDS slice row, write A-fragment to LDS
__device__ __forceinline__ void agg_node(
    int row, int lane, const u16* srow, int dg, const u16* __restrict__ hb,
    u16 aFrag[16][16][8]) {
    int q = lane >> 4;
    int l16 = lane & 15;
    int dgc = dg < MAXDEG ? dg : MAXDEG;
    const uint4* hp = (const uint4*)hb;
    float a0 = 0.f, a1 = 0.f, a2 = 0.f, a3 = 0.f, a4 = 0.f, a5 = 0.f, a6 = 0.f, a7 = 0.f;
#define BACC(v)                                     \
    do {                                            \
        a0 += __uint_as_float((v).x << 16);         \
        a1 += __uint_as_float((v).x & 0xffff0000u); \
        a2 += __uint_as_float((v).y << 16);         \
        a3 += __uint_as_float((v).y & 0xffff0000u); \
        a4 += __uint_as_float((v).z << 16);         \
        a5 += __uint_as_float((v).z & 0xffff0000u); \
        a6 += __uint_as_float((v).w << 16);         \
        a7 += __uint_as_float((v).w & 0xffff0000u); \
    } while (0)
    int e = 0;
    for (; e + 16 <= dgc; e += 16) {
        int i0 = (int)srow[e + q];
        int i1 = (int)srow[e + 4 + q];
        int i2 = (int)srow[e + 8 + q];
        int i3 = (int)srow[e + 12 + q];
        uint4 v0 = hp[i0 * 16 + l16];
        uint4 v1 = hp[i1 * 16 + l16];
        uint4 v2 = hp[i2 * 16 + l16];
        uint4 v3 = hp[i3 * 16 + l16];
        BACC(v0);
        BACC(v1);
        BACC(v2);
        BACC(v3);
    }
    for (; e + 4 <= dgc; e += 4) {
        int i0 = (int)srow[e + q];
        uint4 v = hp[i0 * 16 + l16];
        BACC(v);
    }
    if (e < dgc && e + q < dgc) {
        int i0 = (int)srow[e + q];
        uint4 v = hp[i0 * 16 + l16];
        BACC(v);
    }
#undef BACC
    a0 += __shfl_xor(a0, 16, 64); a1 += __shfl_xor(a1, 16, 64);
    a2 += __shfl_xor(a2, 16, 64); a3 += __shfl_xor(a3, 16, 64);
    a4 += __shfl_xor(a4, 16, 64); a5 += __shfl_xor(a5, 16, 64);
    a6 += __shfl_xor(a6, 16, 64); a7 += __shfl_xor(a7, 16, 64);
    a0 += __shfl_xor(a0, 32, 64); a1 += __shfl_xor(a1, 32, 64);
    a2 += __shfl_xor(a2, 32, 64); a3 += __shfl_xor(a3, 32, 64);
    a4 += __shfl_xor(a4, 32, 64); a5 += __shfl_xor(a5, 32, 64);
    a6 += __shfl_xor(a6, 32, 64); a7 += __shfl_xor(a7, 32, 64);
    if (q == 0) {
        float r = 1.0f / fmaxf((float)dg, 1.0f);
        uint4 o;
        o.x = (u32)f2bf(a0 * r) | ((u32)f2bf(a1 * r) << 16);
        o.y = (u32)f2bf(a2 * r) | ((u32)f2bf(a3 * r) << 16);
        o.z = (u32)f2bf(a4 * r) | ((u32)f2bf(a5 * r) << 16);
        o.w = (u32)f2bf(a6 * r) | ((u32)f2bf(a7 * r) << 16);
        *(uint4*)&aFrag[l16][row][0] = o;  // chunk=l16 (cols l16*8..+7), row in tile
    }
}

// one wave computes one 16-col fragment of relu([hs|hn]@W + b), writing global bf16
__device__ __forceinline__ void mm_frag(
    int n, int lane, int nb, const u16* __restrict__ hsb,
    const u16 aFrag[16][16][8], const u16* __restrict__ Bp,
    const float* __restrict__ bias, u16* __restrict__ outb) {
    int r16 = lane & 15, kb = lane >> 4;
    int arow = nb * 16 + r16;
    const bf16x8* As = (const bf16x8*)hsb;
    const bf16x8* B = (const bf16x8*)Bp;
    f32x4 acc = {0.f, 0.f, 0.f, 0.f};
#pragma unroll
    for (int ks = 0; ks < 8; ks++) {
        bf16x8 a = (ks < 4) ? As[arow * 16 + ks * 4 + kb]
                            : *(const bf16x8*)&aFrag[(ks - 4) * 4 + kb][r16][0];
        bf16x8 b = B[(ks * 8 + n) * 64 + lane];
        acc = __builtin_amdgcn_mfma_f32_16x16x32_bf16(a, b, acc, 0, 0, 0);
    }
    int col = n * 16 + r16;
    float bv = bias[col];
    int orow = nb * 16 + kb * 4;
#pragma unroll
    for (int r = 0; r < 4; r++)
        outb[(orow + r) * 128 + col] = f2bf(fmaxf(acc[r] + bv, 0.f));
}

// same but write relu result into the LDS h2 fragment tile (for classifier)
__device__ __forceinline__ void mm_frag_lds(
    int n, int lane, int nb, const u16* __restrict__ hsb,
    const u16 aFrag[16][16][8], const u16* __restrict__ Bp,
    const float* __restrict__ bias, u16 h2Frag[16][16][8]) {
    int r16 = lane & 15, kb = lane >> 4;
    int arow = nb * 16 + r16;
    const bf16x8* As = (const bf16x8*)hsb;
    const bf16x8* B = (const bf16x8*)Bp;
    f32x4 acc = {0.f, 0.f, 0.f, 0.f};
#pragma unroll
    for (int ks = 0; ks < 8; ks++) {
        bf16x8 a = (ks < 4) ? As[arow * 16 + ks * 4 + kb]
                            : *(const bf16x8*)&aFrag[(ks - 4) * 4 + kb][r16][0];
        bf16x8 b = B[(ks * 8 + n) * 64 + lane];
        acc = __builtin_amdgcn_mfma_f32_16x16x32_bf16(a, b, acc, 0, 0, 0);
    }
    int col = n * 16 + r16;
    float bv = bias[col];
    int ch = col >> 3, el = col & 7;
#pragma unroll
    for (int r = 0; r < 4; r++)
        h2Frag[ch][kb * 4 + r][el] = f2bf(fmaxf(acc[r] + bv, 0.f));
}

// classifier fragment: one wave, 16 cols of out = h2 @ Wc + bc
__device__ __forceinline__ void cls_frag(
    int n, int lane, int nb, const u16 h2Frag[16][16][8],
    const u16* __restrict__ Bc, const float* __restrict__ bc,
    float* __restrict__ out) {
    int r16 = lane & 15, kb = lane >> 4;
    const bf16x8* B = (const bf16x8*)Bc;
    f32x4 acc = {0.f, 0.f, 0.f, 0.f};
#pragma unroll
    for (int ks = 0; ks < 4; ks++) {
        bf16x8 a = *(const bf16x8*)&h2Frag[ks * 4 + kb][r16][0];
        bf16x8 b = B[(ks * 3 + n) * 64 + lane];
        acc = __builtin_amdgcn_mfma_f32_16x16x32_bf16(a, b, acc, 0, 0, 0);
    }
    int col = n * 16 + r16;
    if (col < CLS) {
        float bcv = bc[col];
        int orow = nb * 16 + kb * 4;
#pragma unroll
        for (int r = 0; r < 4; r++)
            out[(orow + r) * CLS + col] = acc[r] + bcv;
    }
}

// ---------------- fuse1: build CSR tile + aggregate L1 + GEMM L1 ----------------
// block = 16 nodes, 8 waves (2 nodes/wave in aggregation), 4 blocks/CU

__global__ __launch_bounds__(TPB_F, 8) void k_fuse1(
    const u32* __restrict__ staged, const u16* __restrict__ cnt,
    const u16* __restrict__ fb, const u16* __restrict__ W1p,
    const float* __restrict__ b1,
    int* __restrict__ deg, u16* __restrict__ edge_srcb, u16* __restrict__ h1b) {
    __shared__ u16 slice[16 * MAXDEG];
    __shared__ u32 ldeg[16];
    __shared__ u16 aFrag[16][16][8];
    int t = threadIdx.x, w = t >> 6, lane = t & 63, nb = blockIdx.x;
    for (int i = t; i < 16 * MAXDEG / 2; i += TPB_F) ((u32*)slice)[i] = 0;
    if (t < 16) ldeg[t] = 0;
    __syncthreads();
    // drain staged cells (LDS atomics only)
    for (int blk = w; blk < 256; blk += 8) {
        int c = (int)cnt[nb * 256 + blk];
        if (lane < c) {
            u32 e = staged[((u32)blk * NBIN + nb) * CAPB + lane];
            int dl = (int)(e >> 14);
            u32 pos = atomicAdd(&ldeg[dl], 1u);
            if (pos < MAXDEG) slice[dl * MAXDEG + pos] = (u16)(e & 0x3fffu);
        }
    }
    __syncthreads();
    // persist CSR tile for fuse2 (coalesced)
    for (int idx = t; idx < 16 * (MAXDEG / 8); idx += TPB_F) {
        int row = idx / (MAXDEG / 8), col = idx % (MAXDEG / 8);
        ((uint4*)(edge_srcb + (size_t)(nb * 16 + row) * MAXDEG))[col] =
            *(const uint4*)&slice[row * MAXDEG + col * 8];
    }
    if (t < 16) deg[nb * 16 + t] = (int)ldeg[t];
    // aggregate: two nodes per wave (w and w+8), from LDS edge list
    agg_node(w, lane, &slice[w * MAXDEG], (int)ldeg[w], fb, aFrag);
    agg_node(w + 8, lane, &slice[(w + 8) * MAXDEG], (int)ldeg[w + 8], fb, aFrag);
    __syncthreads();
    // GEMM: all 8 waves, one 16-col fragment each
    mm_frag(w, lane, nb, fb, aFrag, W1p, b1, h1b);
}

// ---------------- fuse2: load CSR tile + aggregate L2 + GEMM L2 + classifier ----------------

__global__ __launch_bounds__(TPB_F, 8) void k_fuse2(
    const int* __restrict__ deg, const u16* __restrict__ edge_srcb,
    const u16* __restrict__ h1b, const u16* __restrict__ W2p,
    const float* __restrict__ b2, const u16* __restrict__ Wcp,
    const float* __restrict__ bc, float* __restrict__ out) {
    __shared__ u16 slice[16 * MAXDEG];
    __shared__ u32 ldeg[16];
    __shared__ u16 aFrag[16][16][8];
    __shared__ u16 h2Frag[16][16][8];
    int t = threadIdx.x, w = t >> 6, lane = t & 63, nb = blockIdx.x;
    for (int idx = t; idx < 16 * (MAXDEG / 8); idx += TPB_F) {
        int row = idx / (MAXDEG / 8), col = idx % (MAXDEG / 8);
        *(uint4*)&slice[row * MAXDEG + col * 8] =
            ((const uint4*)(edge_srcb + (size_t)(nb * 16 + row) * MAXDEG))[col];
    }
    if (t < 16) ldeg[t] = (u32)deg[nb * 16 + t];
    __syncthreads();
    agg_node(w, lane, &slice[w * MAXDEG], (int)ldeg[w], h1b, aFrag);
    agg_node(w + 8, lane, &slice[(w + 8) * MAXDEG], (int)ldeg[w + 8], h1b, aFrag);
    __syncthreads();
    mm_frag_lds(w, lane, nb, h1b, aFrag, W2p, b2, h2Frag);
    __syncthreads();
    if (w < 3) cls_frag(w, lane, nb, h2Frag, Wcp, bc, out);
}

// ---------------- launch ----------------

static inline size_t align_up(size_t x, size_t a) { return (x + a - 1) & ~(a - 1); }

extern "C" void kernel_launch(void* const* d_in, const int* in_sizes, int n_in,
                              void* d_out, int out_size, void* d_ws, size_t ws_size,
                              hipStream_t stream) {
    const float* features = (const float*)d_in[0];
    const int* edge_index = (const int*)d_in[1];
    const float* Ws1 = (const float*)d_in[2];
    const float* Wn1 = (const float*)d_in[3];
    const float* b1 = (const float*)d_in[4];
    const float* Ws2 = (const float*)d_in[5];
    const float* Wn2 = (const float*)d_in[6];
    const float* b2 = (const float*)d_in[7];
    const float* Wc = (const float*)d_in[8];
    const float* bc = (const float*)d_in[9];
    float* out = (float*)d_out;

    const int* e_src = edge_index;
    const int* e_dst = edge_index + NE;

    char* ws = (char*)d_ws;
    size_t off = 0;
    int* deg = (int*)(ws + off);       off = align_up(off + NN * 4, 512);
    u32* staged = (u32*)(ws + off);    off = align_up(off + (size_t)256 * NBIN * CAPB * 4, 512);
    u16* cnt = (u16*)(ws + off);       off = align_up(off + (size_t)NBIN * 256 * 2, 512);
    u16* edge_srcb = (u16*)(ws + off); off = align_up(off + (size_t)NN * MAXDEG * 2, 512);
    u16* fb = (u16*)(ws + off);        off = align_up(off + (size_t)NN * DIM * 2, 512);
    u16* h1b = (u16*)(ws + off);       off = align_up(off + (size_t)NN * DIM * 2, 512);
    u16* W1p = (u16*)(ws + off);       off = align_up(off + 8 * 8 * 64 * 8 * 2, 512);
    u16* W2p = (u16*)(ws + off);       off = align_up(off + 8 * 8 * 64 * 8 * 2, 512);
    u16* Wcp = (u16*)(ws + off);       off = align_up(off + 4 * 3 * 64 * 8 * 2, 512);

    // P0: bin edges + cvt features + pack weights
    k_prep<<<1541, 256, 0, stream>>>(e_src, e_dst, staged, cnt, features, fb,
                                     Ws1, Wn1, Ws2, Wn2, Wc, W1p, W2p, Wcp);
    // P1: build+agg+mm layer 1 (writes CSR + h1b)
    k_fuse1<<<NN / 16, TPB_F, 0, stream>>>(staged, cnt, fb, W1p, b1,
                                           deg, edge_srcb, h1b);
    // P2: load CSR + agg + mm layer 2 + classifier
    k_fuse2<<<NN / 16, TPB_F, 0, stream>>>(deg, edge_srcb, h1b, W2p, b2,
                                           Wcp, bc, out);
}